// Round 2
// baseline (11382.151 us; speedup 1.0000x reference)
//
#include <hip/hip_runtime.h>
#include <hip/hip_bf16.h>
#include <math.h>

#define B_SZ 4
#define T_LEN 8192
#define C_IN 7
#define NPATCH 1023
#define DIM 512
#define NH 8
#define HD 64
#define NLAYERS 4
#define MLP_HID 2048
#define M_ROWS (B_SZ * NPATCH)   // 4092
#define LN_EPS 1e-5f

// ---------------------------------------------------------------------------
// Patch embedding: emb[b,i,d] = sum_{c,p} x[b, i*8+p, c] * W_emb[c*16+p, d] + b_emb[d]
// Writes emb into d_out[0..M*DIM) and into h (residual stream).
// ---------------------------------------------------------------------------
__global__ __launch_bounds__(128) void embed_kernel(
    const float* __restrict__ x, const float* __restrict__ Wemb,
    const float* __restrict__ bemb, float* __restrict__ emb_out,
    float* __restrict__ h) {
  int row = blockIdx.x;                  // 0..M_ROWS-1
  int b = row / NPATCH, i = row - b * NPATCH;
  __shared__ float patch[112];
  int tid = threadIdx.x;
  if (tid < 112) {
    int c = tid >> 4, p = tid & 15;      // patch vec element [c*16+p] = x[b, i*8+p, c]
    patch[tid] = x[((size_t)b * T_LEN + (size_t)i * 8 + p) * C_IN + c];
  }
  __syncthreads();
  for (int d = tid; d < DIM; d += 128) {
    float acc = bemb[d];
    #pragma unroll 4
    for (int k = 0; k < 112; ++k) acc = fmaf(patch[k], Wemb[k * DIM + d], acc);
    size_t off = (size_t)row * DIM + d;
    emb_out[off] = acc;
    h[off] = acc;
  }
}

// ---------------------------------------------------------------------------
// LayerNorm: one wave (64 lanes) per row of 512.
// ---------------------------------------------------------------------------
__global__ __launch_bounds__(64) void ln_kernel(
    const float* __restrict__ in, const float* __restrict__ g,
    const float* __restrict__ bb, float* __restrict__ out) {
  int row = blockIdx.x;
  int lane = threadIdx.x;
  const float* xr = in + (size_t)row * DIM;
  float v[8];
  float s = 0.f;
  #pragma unroll
  for (int k = 0; k < 8; ++k) { v[k] = xr[lane + 64 * k]; s += v[k]; }
  #pragma unroll
  for (int off = 32; off; off >>= 1) s += __shfl_down(s, off);
  s = __shfl(s, 0);
  float mu = s * (1.f / DIM);
  float q = 0.f;
  #pragma unroll
  for (int k = 0; k < 8; ++k) { float d = v[k] - mu; q = fmaf(d, d, q); }
  #pragma unroll
  for (int off = 32; off; off >>= 1) q += __shfl_down(q, off);
  q = __shfl(q, 0);
  float rstd = rsqrtf(q * (1.f / DIM) + LN_EPS);
  float* orow = out + (size_t)row * DIM;
  #pragma unroll
  for (int k = 0; k < 8; ++k) {
    int d = lane + 64 * k;
    orow[d] = (v[k] - mu) * rstd * g[d] + bb[d];
  }
}

// ---------------------------------------------------------------------------
// fp32 tiled GEMM: C[M,N] = epi(A[M,K] @ W[K,N] + bias [+ res])
// EPI: 0 = bias only, 1 = bias + residual, 2 = bias + exact GELU.
// 64x64 block tile, 256 threads, 4x4 micro-tile, BK=16.
// As padded [64][17] -> conflict-free column reads.
// ---------------------------------------------------------------------------
template <int EPI>
__global__ __launch_bounds__(256) void gemm_kernel(
    const float* __restrict__ A, const float* __restrict__ W,
    const float* __restrict__ bias, const float* __restrict__ res,
    float* __restrict__ C, int M, int N, int K) {
  __shared__ float As[64][17];
  __shared__ float Bs[16][64];
  const int bm = blockIdx.y * 64;
  const int bn = blockIdx.x * 64;
  const int tid = threadIdx.x;
  const int tr = tid >> 4;   // 0..15 row group (4 rows each)
  const int tc = tid & 15;   // 0..15 col group (4 cols each)
  float acc[4][4] = {{0.f}};

  for (int k0 = 0; k0 < K; k0 += 16) {
    {
      int r = tid >> 2;
      int c = (tid & 3) << 2;
      int gm = bm + r;
      float4 av = make_float4(0.f, 0.f, 0.f, 0.f);
      if (gm < M) av = *(const float4*)(A + (size_t)gm * K + k0 + c);
      As[r][c] = av.x; As[r][c + 1] = av.y; As[r][c + 2] = av.z; As[r][c + 3] = av.w;
    }
    {
      int r = tid >> 4;
      int c = (tid & 15) << 2;
      float4 wv = *(const float4*)(W + (size_t)(k0 + r) * N + bn + c);
      Bs[r][c] = wv.x; Bs[r][c + 1] = wv.y; Bs[r][c + 2] = wv.z; Bs[r][c + 3] = wv.w;
    }
    __syncthreads();
    #pragma unroll
    for (int k = 0; k < 16; ++k) {
      float a[4], bq[4];
      #pragma unroll
      for (int r = 0; r < 4; ++r) a[r] = As[tr * 4 + r][k];
      #pragma unroll
      for (int c = 0; c < 4; ++c) bq[c] = Bs[k][tc * 4 + c];
      #pragma unroll
      for (int r = 0; r < 4; ++r)
        #pragma unroll
        for (int c = 0; c < 4; ++c)
          acc[r][c] = fmaf(a[r], bq[c], acc[r][c]);
    }
    __syncthreads();
  }

  float4 bv = *(const float4*)(bias + bn + tc * 4);
  #pragma unroll
  for (int r = 0; r < 4; ++r) {
    int gm = bm + tr * 4 + r;
    if (gm >= M) continue;
    size_t off = (size_t)gm * N + bn + tc * 4;
    float4 v;
    v.x = acc[r][0] + bv.x;
    v.y = acc[r][1] + bv.y;
    v.z = acc[r][2] + bv.z;
    v.w = acc[r][3] + bv.w;
    if (EPI == 1) {
      float4 rv = *(const float4*)(res + off);
      v.x += rv.x; v.y += rv.y; v.z += rv.z; v.w += rv.w;
    } else if (EPI == 2) {
      v.x = 0.5f * v.x * (1.f + erff(v.x * 0.70710678118f));
      v.y = 0.5f * v.y * (1.f + erff(v.y * 0.70710678118f));
      v.z = 0.5f * v.z * (1.f + erff(v.z * 0.70710678118f));
      v.w = 0.5f * v.w * (1.f + erff(v.w * 0.70710678118f));
    }
    *(float4*)(C + off) = v;
  }
}

// ---------------------------------------------------------------------------
// RoPE applied in-place to q and k halves of qkv[b,i, s*512 + h*64 + d].
// angle(j, i) = i * 10000^(-j/32), pairs (d=j, d=j+32) per head.
// ---------------------------------------------------------------------------
__global__ __launch_bounds__(256) void rope_kernel(float* __restrict__ qkv) {
  int row = blockIdx.x;
  int i = row % NPATCH;
  float* base = qkv + (size_t)row * (3 * DIM);
  int tid = threadIdx.x;
  for (int p = tid; p < 512; p += 256) {   // 2 (q,k) * 8 heads * 32 pairs
    int s = p >> 8;
    int hh = (p >> 5) & 7;
    int j = p & 31;
    float inv = powf(10000.0f, -(float)j * (1.0f / 32.0f));
    float th = (float)i * inv;
    float sn, cs;
    sincosf(th, &sn, &cs);
    int idx = s * DIM + hh * HD + j;
    float a = base[idx];
    float b2 = base[idx + 32];
    base[idx]      = a * cs - b2 * sn;
    base[idx + 32] = b2 * cs + a * sn;
  }
}

// ---------------------------------------------------------------------------
// Attention: one block per (b, h, 4-query tile). Two-pass softmax, scores in
// LDS (4 x 1023 floats). K/V rows loaded once per block, reused for 4 queries.
// ---------------------------------------------------------------------------
__global__ __launch_bounds__(256) void attn_kernel(
    const float* __restrict__ qkv, float* __restrict__ o) {
  const int qi0 = blockIdx.x * 4;
  const int h = blockIdx.y;
  const int b = blockIdx.z;
  const int tid = threadIdx.x;
  __shared__ __align__(16) float qv[4][64];
  __shared__ float sc[4][NPATCH];
  __shared__ float l_sh[4];
  __shared__ float oacc[4][4][64];

  {
    int q = tid >> 6, d = tid & 63;
    int qi = qi0 + q;
    float val = 0.f;
    if (qi < NPATCH)
      val = qkv[(size_t)(b * NPATCH + qi) * (3 * DIM) + h * HD + d] * 0.125f;
    qv[q][d] = val;
  }
  __syncthreads();

  // scores
  for (int j = tid; j < NPATCH; j += 256) {
    const float4* k4 = (const float4*)(qkv + (size_t)(b * NPATCH + j) * (3 * DIM) + DIM + h * HD);
    float s0 = 0.f, s1 = 0.f, s2 = 0.f, s3 = 0.f;
    #pragma unroll
    for (int dd = 0; dd < 16; ++dd) {
      float4 kv = k4[dd];
      float4 q0 = *(const float4*)&qv[0][dd * 4];
      float4 q1 = *(const float4*)&qv[1][dd * 4];
      float4 q2 = *(const float4*)&qv[2][dd * 4];
      float4 q3 = *(const float4*)&qv[3][dd * 4];
      s0 += q0.x * kv.x + q0.y * kv.y + q0.z * kv.z + q0.w * kv.w;
      s1 += q1.x * kv.x + q1.y * kv.y + q1.z * kv.z + q1.w * kv.w;
      s2 += q2.x * kv.x + q2.y * kv.y + q2.z * kv.z + q2.w * kv.w;
      s3 += q3.x * kv.x + q3.y * kv.y + q3.z * kv.z + q3.w * kv.w;
    }
    sc[0][j] = s0; sc[1][j] = s1; sc[2][j] = s2; sc[3][j] = s3;
  }
  __syncthreads();

  // softmax: wave w handles query w
  {
    int w = tid >> 6, lane = tid & 63;
    float m = -1e30f;
    for (int j = lane; j < NPATCH; j += 64) m = fmaxf(m, sc[w][j]);
    #pragma unroll
    for (int off = 32; off; off >>= 1) m = fmaxf(m, __shfl_down(m, off));
    m = __shfl(m, 0);
    float l = 0.f;
    for (int j = lane; j < NPATCH; j += 64) {
      float pv = __expf(sc[w][j] - m);
      sc[w][j] = pv;
      l += pv;
    }
    #pragma unroll
    for (int off = 32; off; off >>= 1) l += __shfl_down(l, off);
    if (lane == 0) l_sh[w] = l;
  }
  __syncthreads();

  // P @ V
  {
    int d = tid & 63, jg = tid >> 6;
    float a0 = 0.f, a1 = 0.f, a2 = 0.f, a3 = 0.f;
    for (int j = jg; j < NPATCH; j += 4) {
      float vv = qkv[(size_t)(b * NPATCH + j) * (3 * DIM) + 2 * DIM + h * HD + d];
      a0 = fmaf(sc[0][j], vv, a0);
      a1 = fmaf(sc[1][j], vv, a1);
      a2 = fmaf(sc[2][j], vv, a2);
      a3 = fmaf(sc[3][j], vv, a3);
    }
    oacc[0][jg][d] = a0; oacc[1][jg][d] = a1;
    oacc[2][jg][d] = a2; oacc[3][jg][d] = a3;
  }
  __syncthreads();
  {
    int q = tid >> 6, d = tid & 63;
    int qi = qi0 + q;
    if (qi < NPATCH) {
      float r = (oacc[q][0][d] + oacc[q][1][d] + oacc[q][2][d] + oacc[q][3][d]) / l_sh[q];
      o[(size_t)(b * NPATCH + qi) * DIM + h * HD + d] = r;
    }
  }
}

// ---------------------------------------------------------------------------
extern "C" void kernel_launch(void* const* d_in, const int* in_sizes, int n_in,
                              void* d_out, int out_size, void* d_ws, size_t ws_size,
                              hipStream_t stream) {
  const float* x      = (const float*)d_in[0];
  const float* W_emb  = (const float*)d_in[1];
  const float* b_emb  = (const float*)d_in[2];
  const float* ln1_g  = (const float*)d_in[3];
  const float* ln1_b  = (const float*)d_in[4];
  const float* W_qkv  = (const float*)d_in[5];
  const float* b_qkv  = (const float*)d_in[6];
  const float* W_proj = (const float*)d_in[7];
  const float* b_proj = (const float*)d_in[8];
  const float* ln2_g  = (const float*)d_in[9];
  const float* ln2_b  = (const float*)d_in[10];
  const float* W_mlp1 = (const float*)d_in[11];
  const float* b_mlp1 = (const float*)d_in[12];
  const float* W_mlp2 = (const float*)d_in[13];
  const float* b_mlp2 = (const float*)d_in[14];
  const float* lnf_g  = (const float*)d_in[15];
  const float* lnf_b  = (const float*)d_in[16];
  float* out = (float*)d_out;

  // workspace layout (floats): h | y(=o, disjoint lifetimes) | qkv/mid
  // total = M*(512 + 512 + 2048) * 4B = 50.3 MB
  float* h   = (float*)d_ws;
  float* y   = h + (size_t)M_ROWS * DIM;
  float* o   = y;                              // alias: y dead after qkv GEMM, reborn at ln2
  float* qkv = y + (size_t)M_ROWS * DIM;
  float* mid = qkv;                            // alias: qkv dead after attention

  embed_kernel<<<M_ROWS, 128, 0, stream>>>(x, W_emb, b_emb, out, h);

  for (int L = 0; L < NLAYERS; ++L) {
    ln_kernel<<<M_ROWS, 64, 0, stream>>>(h, ln1_g + L * DIM, ln1_b + L * DIM, y);
    gemm_kernel<0><<<dim3(3 * DIM / 64, (M_ROWS + 63) / 64), 256, 0, stream>>>(
        y, W_qkv + (size_t)L * DIM * 3 * DIM, b_qkv + L * 3 * DIM, nullptr, qkv,
        M_ROWS, 3 * DIM, DIM);
    rope_kernel<<<M_ROWS, 256, 0, stream>>>(qkv);
    attn_kernel<<<dim3((NPATCH + 3) / 4, NH, B_SZ), 256, 0, stream>>>(qkv, o);
    gemm_kernel<1><<<dim3(DIM / 64, (M_ROWS + 63) / 64), 256, 0, stream>>>(
        o, W_proj + (size_t)L * DIM * DIM, b_proj + L * DIM, h, h, M_ROWS, DIM, DIM);
    ln_kernel<<<M_ROWS, 64, 0, stream>>>(h, ln2_g + L * DIM, ln2_b + L * DIM, y);
    gemm_kernel<2><<<dim3(MLP_HID / 64, (M_ROWS + 63) / 64), 256, 0, stream>>>(
        y, W_mlp1 + (size_t)L * DIM * MLP_HID, b_mlp1 + L * MLP_HID, nullptr, mid,
        M_ROWS, MLP_HID, DIM);
    gemm_kernel<1><<<dim3(DIM / 64, (M_ROWS + 63) / 64), 256, 0, stream>>>(
        mid, W_mlp2 + (size_t)L * MLP_HID * DIM, b_mlp2 + L * DIM, h, h,
        M_ROWS, DIM, MLP_HID);
  }

  ln_kernel<<<M_ROWS, 64, 0, stream>>>(h, lnf_g, lnf_b, out + (size_t)M_ROWS * DIM);
}

// Round 3
// 2882.698 us; speedup vs baseline: 3.9484x; 3.9484x over previous
//
#include <hip/hip_runtime.h>
#include <hip/hip_bf16.h>
#include <math.h>

#define B_SZ 4
#define T_LEN 8192
#define C_IN 7
#define NPATCH 1023
#define DIM 512
#define NH 8
#define HD 64
#define NLAYERS 4
#define MLP_HID 2048
#define M_ROWS (B_SZ * NPATCH)   // 4092
#define LN_EPS 1e-5f

// ---------------------------------------------------------------------------
// Patch embedding: emb[b,i,d] = sum_{c,p} x[b, i*8+p, c] * W_emb[c*16+p, d] + b_emb[d]
// ---------------------------------------------------------------------------
__global__ __launch_bounds__(128) void embed_kernel(
    const float* __restrict__ x, const float* __restrict__ Wemb,
    const float* __restrict__ bemb, float* __restrict__ emb_out,
    float* __restrict__ h) {
  int row = blockIdx.x;                  // 0..M_ROWS-1
  int b = row / NPATCH, i = row - b * NPATCH;
  __shared__ float patch[112];
  int tid = threadIdx.x;
  if (tid < 112) {
    int c = tid >> 4, p = tid & 15;      // patch vec element [c*16+p] = x[b, i*8+p, c]
    patch[tid] = x[((size_t)b * T_LEN + (size_t)i * 8 + p) * C_IN + c];
  }
  __syncthreads();
  for (int d = tid; d < DIM; d += 128) {
    float acc = bemb[d];
    #pragma unroll 4
    for (int k = 0; k < 112; ++k) acc = fmaf(patch[k], Wemb[k * DIM + d], acc);
    size_t off = (size_t)row * DIM + d;
    emb_out[off] = acc;
    h[off] = acc;
  }
}

// ---------------------------------------------------------------------------
// LayerNorm: one wave (64 lanes) per row of 512.
// ---------------------------------------------------------------------------
__global__ __launch_bounds__(64) void ln_kernel(
    const float* __restrict__ in, const float* __restrict__ g,
    const float* __restrict__ bb, float* __restrict__ out) {
  int row = blockIdx.x;
  int lane = threadIdx.x;
  const float* xr = in + (size_t)row * DIM;
  float v[8];
  float s = 0.f;
  #pragma unroll
  for (int k = 0; k < 8; ++k) { v[k] = xr[lane + 64 * k]; s += v[k]; }
  #pragma unroll
  for (int off = 32; off; off >>= 1) s += __shfl_down(s, off);
  s = __shfl(s, 0);
  float mu = s * (1.f / DIM);
  float q = 0.f;
  #pragma unroll
  for (int k = 0; k < 8; ++k) { float d = v[k] - mu; q = fmaf(d, d, q); }
  #pragma unroll
  for (int off = 32; off; off >>= 1) q += __shfl_down(q, off);
  q = __shfl(q, 0);
  float rstd = rsqrtf(q * (1.f / DIM) + LN_EPS);
  float* orow = out + (size_t)row * DIM;
  #pragma unroll
  for (int k = 0; k < 8; ++k) {
    int d = lane + 64 * k;
    orow[d] = (v[k] - mu) * rstd * g[d] + bb[d];
  }
}

// ---------------------------------------------------------------------------
// fp32 tiled GEMM (unchanged from R1 — passed).
// ---------------------------------------------------------------------------
template <int EPI>
__global__ __launch_bounds__(256) void gemm_kernel(
    const float* __restrict__ A, const float* __restrict__ W,
    const float* __restrict__ bias, const float* __restrict__ res,
    float* __restrict__ C, int M, int N, int K) {
  __shared__ float As[64][17];
  __shared__ float Bs[16][64];
  const int bm = blockIdx.y * 64;
  const int bn = blockIdx.x * 64;
  const int tid = threadIdx.x;
  const int tr = tid >> 4;
  const int tc = tid & 15;
  float acc[4][4] = {{0.f}};

  for (int k0 = 0; k0 < K; k0 += 16) {
    {
      int r = tid >> 2;
      int c = (tid & 3) << 2;
      int gm = bm + r;
      float4 av = make_float4(0.f, 0.f, 0.f, 0.f);
      if (gm < M) av = *(const float4*)(A + (size_t)gm * K + k0 + c);
      As[r][c] = av.x; As[r][c + 1] = av.y; As[r][c + 2] = av.z; As[r][c + 3] = av.w;
    }
    {
      int r = tid >> 4;
      int c = (tid & 15) << 2;
      float4 wv = *(const float4*)(W + (size_t)(k0 + r) * N + bn + c);
      Bs[r][c] = wv.x; Bs[r][c + 1] = wv.y; Bs[r][c + 2] = wv.z; Bs[r][c + 3] = wv.w;
    }
    __syncthreads();
    #pragma unroll
    for (int k = 0; k < 16; ++k) {
      float a[4], bq[4];
      #pragma unroll
      for (int r = 0; r < 4; ++r) a[r] = As[tr * 4 + r][k];
      #pragma unroll
      for (int c = 0; c < 4; ++c) bq[c] = Bs[k][tc * 4 + c];
      #pragma unroll
      for (int r = 0; r < 4; ++r)
        #pragma unroll
        for (int c = 0; c < 4; ++c)
          acc[r][c] = fmaf(a[r], bq[c], acc[r][c]);
    }
    __syncthreads();
  }

  float4 bv = *(const float4*)(bias + bn + tc * 4);
  #pragma unroll
  for (int r = 0; r < 4; ++r) {
    int gm = bm + tr * 4 + r;
    if (gm >= M) continue;
    size_t off = (size_t)gm * N + bn + tc * 4;
    float4 v;
    v.x = acc[r][0] + bv.x;
    v.y = acc[r][1] + bv.y;
    v.z = acc[r][2] + bv.z;
    v.w = acc[r][3] + bv.w;
    if (EPI == 1) {
      float4 rv = *(const float4*)(res + off);
      v.x += rv.x; v.y += rv.y; v.z += rv.z; v.w += rv.w;
    } else if (EPI == 2) {
      v.x = 0.5f * v.x * (1.f + erff(v.x * 0.70710678118f));
      v.y = 0.5f * v.y * (1.f + erff(v.y * 0.70710678118f));
      v.z = 0.5f * v.z * (1.f + erff(v.z * 0.70710678118f));
      v.w = 0.5f * v.w * (1.f + erff(v.w * 0.70710678118f));
    }
    *(float4*)(C + off) = v;
  }
}

// ---------------------------------------------------------------------------
// RoPE (unchanged).
// ---------------------------------------------------------------------------
__global__ __launch_bounds__(256) void rope_kernel(float* __restrict__ qkv) {
  int row = blockIdx.x;
  int i = row % NPATCH;
  float* base = qkv + (size_t)row * (3 * DIM);
  int tid = threadIdx.x;
  for (int p = tid; p < 512; p += 256) {
    int s = p >> 8;
    int hh = (p >> 5) & 7;
    int j = p & 31;
    float inv = powf(10000.0f, -(float)j * (1.0f / 32.0f));
    float th = (float)i * inv;
    float sn, cs;
    sincosf(th, &sn, &cs);
    int idx = s * DIM + hh * HD + j;
    float a = base[idx];
    float b2 = base[idx + 32];
    base[idx]      = a * cs - b2 * sn;
    base[idx + 32] = b2 * cs + a * sn;
  }
}

// ---------------------------------------------------------------------------
// Flash-style attention: one block per (b, h, 32-query tile). 256 threads.
// Iterate 64-key tiles; K/V staged in LDS (row stride 65 -> conflict-free
// lane-strided reads); online softmax (m, l, alpha in LDS); O in registers.
// S phase: thread (tq=tid>>5, tk=tid&31) computes q in {tq+8i}, k in {tk, tk+32}.
// PV phase: thread (to=tid>>5, td=tid&31) owns q in {to+8i}, d in {td, td+32}.
// ---------------------------------------------------------------------------
#define QT 32
#define JT 64
#define LPAD 65

__global__ __launch_bounds__(256) void attn_kernel(
    const float* __restrict__ qkv, float* __restrict__ o) {
  const int qt0 = blockIdx.x * QT;
  const int h = blockIdx.y;
  const int b = blockIdx.z;
  const int tid = threadIdx.x;

  __shared__ float Qs[QT][LPAD];
  __shared__ float Ks[JT][LPAD];
  __shared__ float Vs[JT][LPAD];
  __shared__ float Ps[QT][LPAD];
  __shared__ float m_run[QT], l_run[QT], alpha_s[QT];

  // ---- load Q tile (scaled by 1/8), zero-pad invalid rows ----
  {
    int r = tid >> 3;             // 0..31
    int c0 = (tid & 7) * 8;       // 0..56 step 8
    int qi = qt0 + r;
    if (qi < NPATCH) {
      const float4* src = (const float4*)(qkv + (size_t)(b * NPATCH + qi) * (3 * DIM) + h * HD + c0);
      float4 v0 = src[0], v1 = src[1];
      Qs[r][c0 + 0] = v0.x * 0.125f; Qs[r][c0 + 1] = v0.y * 0.125f;
      Qs[r][c0 + 2] = v0.z * 0.125f; Qs[r][c0 + 3] = v0.w * 0.125f;
      Qs[r][c0 + 4] = v1.x * 0.125f; Qs[r][c0 + 5] = v1.y * 0.125f;
      Qs[r][c0 + 6] = v1.z * 0.125f; Qs[r][c0 + 7] = v1.w * 0.125f;
    } else {
      #pragma unroll
      for (int u = 0; u < 8; ++u) Qs[r][c0 + u] = 0.f;
    }
  }
  if (tid < QT) { m_run[tid] = -1e30f; l_run[tid] = 0.f; }

  float acc[4][2] = {{0.f, 0.f}, {0.f, 0.f}, {0.f, 0.f}, {0.f, 0.f}};
  __syncthreads();

  for (int j0 = 0; j0 < NPATCH; j0 += JT) {
    // ---- stage K,V tiles (zero-pad invalid keys) ----
    {
      int r = tid >> 2;              // 0..63
      int c0 = (tid & 3) * 16;       // 0,16,32,48
      int j = j0 + r;
      if (j < NPATCH) {
        const float* base = qkv + (size_t)(b * NPATCH + j) * (3 * DIM) + h * HD;
        const float4* ksrc = (const float4*)(base + DIM + c0);
        const float4* vsrc = (const float4*)(base + 2 * DIM + c0);
        #pragma unroll
        for (int u = 0; u < 4; ++u) {
          float4 kv = ksrc[u];
          Ks[r][c0 + u * 4 + 0] = kv.x; Ks[r][c0 + u * 4 + 1] = kv.y;
          Ks[r][c0 + u * 4 + 2] = kv.z; Ks[r][c0 + u * 4 + 3] = kv.w;
          float4 vv = vsrc[u];
          Vs[r][c0 + u * 4 + 0] = vv.x; Vs[r][c0 + u * 4 + 1] = vv.y;
          Vs[r][c0 + u * 4 + 2] = vv.z; Vs[r][c0 + u * 4 + 3] = vv.w;
        }
      } else {
        #pragma unroll
        for (int u = 0; u < 16; ++u) { Ks[r][c0 + u] = 0.f; Vs[r][c0 + u] = 0.f; }
      }
    }
    __syncthreads();

    // ---- S = Q K^T for this tile ----
    {
      int tq = tid >> 5;     // 0..7
      int tk = tid & 31;     // 0..31
      float s[4][2] = {{0.f, 0.f}, {0.f, 0.f}, {0.f, 0.f}, {0.f, 0.f}};
      for (int d = 0; d < HD; ++d) {
        float k0 = Ks[tk][d];
        float k1 = Ks[tk + 32][d];
        #pragma unroll
        for (int i = 0; i < 4; ++i) {
          float qv = Qs[tq + 8 * i][d];
          s[i][0] = fmaf(qv, k0, s[i][0]);
          s[i][1] = fmaf(qv, k1, s[i][1]);
        }
      }
      bool val0 = (j0 + tk) < NPATCH;
      bool val1 = (j0 + tk + 32) < NPATCH;
      #pragma unroll
      for (int i = 0; i < 4; ++i) {
        Ps[tq + 8 * i][tk]      = val0 ? s[i][0] : -1e30f;
        Ps[tq + 8 * i][tk + 32] = val1 ? s[i][1] : -1e30f;
      }
    }
    __syncthreads();

    // ---- online softmax update (thread r handles query row r) ----
    if (tid < QT) {
      float mold = m_run[tid];
      float tmax = mold;
      for (int j = 0; j < JT; ++j) tmax = fmaxf(tmax, Ps[tid][j]);
      float al = __expf(mold - tmax);
      float ts = 0.f;
      for (int j = 0; j < JT; ++j) {
        float p = __expf(Ps[tid][j] - tmax);
        Ps[tid][j] = p;
        ts += p;
      }
      m_run[tid] = tmax;
      l_run[tid] = l_run[tid] * al + ts;
      alpha_s[tid] = al;
    }
    __syncthreads();

    // ---- O = alpha*O + P V ----
    {
      int to = tid >> 5;     // 0..7
      int td = tid & 31;     // 0..31
      #pragma unroll
      for (int i = 0; i < 4; ++i) {
        float al = alpha_s[to + 8 * i];
        acc[i][0] *= al;
        acc[i][1] *= al;
      }
      for (int j = 0; j < JT; ++j) {
        float v0 = Vs[j][td];
        float v1 = Vs[j][td + 32];
        #pragma unroll
        for (int i = 0; i < 4; ++i) {
          float p = Ps[to + 8 * i][j];
          acc[i][0] = fmaf(p, v0, acc[i][0]);
          acc[i][1] = fmaf(p, v1, acc[i][1]);
        }
      }
    }
    __syncthreads();
  }

  // ---- write O ----
  {
    int to = tid >> 5;
    int td = tid & 31;
    #pragma unroll
    for (int i = 0; i < 4; ++i) {
      int q = to + 8 * i;
      int qi = qt0 + q;
      if (qi < NPATCH) {
        float inv = 1.f / l_run[q];
        size_t off = (size_t)(b * NPATCH + qi) * DIM + h * HD + td;
        o[off]      = acc[i][0] * inv;
        o[off + 32] = acc[i][1] * inv;
      }
    }
  }
}

// ---------------------------------------------------------------------------
extern "C" void kernel_launch(void* const* d_in, const int* in_sizes, int n_in,
                              void* d_out, int out_size, void* d_ws, size_t ws_size,
                              hipStream_t stream) {
  const float* x      = (const float*)d_in[0];
  const float* W_emb  = (const float*)d_in[1];
  const float* b_emb  = (const float*)d_in[2];
  const float* ln1_g  = (const float*)d_in[3];
  const float* ln1_b  = (const float*)d_in[4];
  const float* W_qkv  = (const float*)d_in[5];
  const float* b_qkv  = (const float*)d_in[6];
  const float* W_proj = (const float*)d_in[7];
  const float* b_proj = (const float*)d_in[8];
  const float* ln2_g  = (const float*)d_in[9];
  const float* ln2_b  = (const float*)d_in[10];
  const float* W_mlp1 = (const float*)d_in[11];
  const float* b_mlp1 = (const float*)d_in[12];
  const float* W_mlp2 = (const float*)d_in[13];
  const float* b_mlp2 = (const float*)d_in[14];
  const float* lnf_g  = (const float*)d_in[15];
  const float* lnf_b  = (const float*)d_in[16];
  float* out = (float*)d_out;

  // workspace layout (floats): h | y(=o, disjoint lifetimes) | qkv/mid
  float* h   = (float*)d_ws;
  float* y   = h + (size_t)M_ROWS * DIM;
  float* o   = y;                              // alias: y dead after qkv GEMM, reborn at ln2
  float* qkv = y + (size_t)M_ROWS * DIM;
  float* mid = qkv;                            // alias: qkv dead after attention

  embed_kernel<<<M_ROWS, 128, 0, stream>>>(x, W_emb, b_emb, out, h);

  for (int L = 0; L < NLAYERS; ++L) {
    ln_kernel<<<M_ROWS, 64, 0, stream>>>(h, ln1_g + L * DIM, ln1_b + L * DIM, y);
    gemm_kernel<0><<<dim3(3 * DIM / 64, (M_ROWS + 63) / 64), 256, 0, stream>>>(
        y, W_qkv + (size_t)L * DIM * 3 * DIM, b_qkv + L * 3 * DIM, nullptr, qkv,
        M_ROWS, 3 * DIM, DIM);
    rope_kernel<<<M_ROWS, 256, 0, stream>>>(qkv);
    attn_kernel<<<dim3((NPATCH + QT - 1) / QT, NH, B_SZ), 256, 0, stream>>>(qkv, o);
    gemm_kernel<1><<<dim3(DIM / 64, (M_ROWS + 63) / 64), 256, 0, stream>>>(
        o, W_proj + (size_t)L * DIM * DIM, b_proj + L * DIM, h, h, M_ROWS, DIM, DIM);
    ln_kernel<<<M_ROWS, 64, 0, stream>>>(h, ln2_g + L * DIM, ln2_b + L * DIM, y);
    gemm_kernel<2><<<dim3(MLP_HID / 64, (M_ROWS + 63) / 64), 256, 0, stream>>>(
        y, W_mlp1 + (size_t)L * DIM * MLP_HID, b_mlp1 + L * MLP_HID, nullptr, mid,
        M_ROWS, MLP_HID, DIM);
    gemm_kernel<1><<<dim3(DIM / 64, (M_ROWS + 63) / 64), 256, 0, stream>>>(
        mid, W_mlp2 + (size_t)L * MLP_HID * DIM, b_mlp2 + L * DIM, h, h,
        M_ROWS, DIM, MLP_HID);
  }

  ln_kernel<<<M_ROWS, 64, 0, stream>>>(h, lnf_g, lnf_b, out + (size_t)M_ROWS * DIM);
}

// Round 4
// 1923.013 us; speedup vs baseline: 5.9189x; 1.4991x over previous
//
#include <hip/hip_runtime.h>
#include <hip/hip_bf16.h>
#include <math.h>

#define B_SZ 4
#define T_LEN 8192
#define C_IN 7
#define NPATCH 1023
#define DIM 512
#define NH 8
#define HD 64
#define NLAYERS 4
#define MLP_HID 2048
#define M_ROWS (B_SZ * NPATCH)   // 4092
#define LN_EPS 1e-5f

typedef __attribute__((ext_vector_type(8))) short short8;
typedef __attribute__((ext_vector_type(4))) float float4v;

static __device__ __forceinline__ unsigned short f2bf(float f) {
  __hip_bfloat16 h = __float2bfloat16(f);
  return *reinterpret_cast<unsigned short*>(&h);
}

// ---------------------------------------------------------------------------
// Patch embedding (unchanged, fp32 — keeps emb output exact).
// ---------------------------------------------------------------------------
__global__ __launch_bounds__(128) void embed_kernel(
    const float* __restrict__ x, const float* __restrict__ Wemb,
    const float* __restrict__ bemb, float* __restrict__ emb_out,
    float* __restrict__ h) {
  int row = blockIdx.x;
  int b = row / NPATCH, i = row - b * NPATCH;
  __shared__ float patch[112];
  int tid = threadIdx.x;
  if (tid < 112) {
    int c = tid >> 4, p = tid & 15;
    patch[tid] = x[((size_t)b * T_LEN + (size_t)i * 8 + p) * C_IN + c];
  }
  __syncthreads();
  for (int d = tid; d < DIM; d += 128) {
    float acc = bemb[d];
    #pragma unroll 4
    for (int k = 0; k < 112; ++k) acc = fmaf(patch[k], Wemb[k * DIM + d], acc);
    size_t off = (size_t)row * DIM + d;
    emb_out[off] = acc;
    h[off] = acc;
  }
}

// ---------------------------------------------------------------------------
// LayerNorm: one wave per row. BF=true -> bf16 output (GEMM A operand).
// ---------------------------------------------------------------------------
template <bool BF>
__global__ __launch_bounds__(64) void ln_kernel(
    const float* __restrict__ in, const float* __restrict__ g,
    const float* __restrict__ bb, void* __restrict__ outv) {
  int row = blockIdx.x;
  int lane = threadIdx.x;
  const float* xr = in + (size_t)row * DIM;
  float v[8];
  float s = 0.f;
  #pragma unroll
  for (int k = 0; k < 8; ++k) { v[k] = xr[lane + 64 * k]; s += v[k]; }
  #pragma unroll
  for (int off = 32; off; off >>= 1) s += __shfl_down(s, off);
  s = __shfl(s, 0);
  float mu = s * (1.f / DIM);
  float q = 0.f;
  #pragma unroll
  for (int k = 0; k < 8; ++k) { float d = v[k] - mu; q = fmaf(d, d, q); }
  #pragma unroll
  for (int off = 32; off; off >>= 1) q += __shfl_down(q, off);
  q = __shfl(q, 0);
  float rstd = rsqrtf(q * (1.f / DIM) + LN_EPS);
  #pragma unroll
  for (int k = 0; k < 8; ++k) {
    int d = lane + 64 * k;
    float r = (v[k] - mu) * rstd * g[d] + bb[d];
    if (BF)
      ((unsigned short*)outv)[(size_t)row * DIM + d] = f2bf(r);
    else
      ((float*)outv)[(size_t)row * DIM + d] = r;
  }
}

// ---------------------------------------------------------------------------
// Weight convert + transpose: W[K][N] fp32 -> Wt[N][K] bf16 (per layer z).
// ---------------------------------------------------------------------------
__global__ __launch_bounds__(256) void wcvt_kernel(
    const float* __restrict__ W, unsigned short* __restrict__ Wt, int K, int N) {
  __shared__ float tile[32][33];
  int n0 = blockIdx.x * 32, k0 = blockIdx.y * 32, L = blockIdx.z;
  const float* Ws = W + (size_t)L * K * N;
  unsigned short* Wd = Wt + (size_t)L * K * N;
  int tx = threadIdx.x & 31, ty = threadIdx.x >> 5;
  #pragma unroll
  for (int i = 0; i < 4; ++i)
    tile[ty + i * 8][tx] = Ws[(size_t)(k0 + ty + i * 8) * N + n0 + tx];
  __syncthreads();
  #pragma unroll
  for (int i = 0; i < 4; ++i)
    Wd[(size_t)(n0 + ty + i * 8) * K + k0 + tx] = f2bf(tile[tx][ty + i * 8]);
}

// ---------------------------------------------------------------------------
// bf16 MFMA GEMM: C[M][N] = epi(A[M][K] @ Wt[N][K]^T + bias [+res]).
// 128x128 tile, BK=32, 4 waves, each wave 64x64 (4x4 of 16x16x32 MFMA).
// LDS rows padded to 40 bf16 (80 B = 20 banks): fragment ds_read_b128 is
// 2-way bank-aliased only (free, m136). Fragment layouts per m89/m91/m120:
//   A/B operand: free index = lane&15, k = (lane>>4)*8 + j (8 contiguous).
//   C/D: row (m) = (lane>>4)*4 + reg, col (n) = lane&15.
// EPI: 0 = bias -> fp32; 1 = bias + res -> fp32; 2 = bias + GELU -> bf16.
// ---------------------------------------------------------------------------
template <int EPI>
__global__ __launch_bounds__(256) void mfma_gemm(
    const unsigned short* __restrict__ A, const unsigned short* __restrict__ Bt,
    const float* __restrict__ bias, const float* __restrict__ res,
    float* __restrict__ Cf, unsigned short* __restrict__ Cb,
    int M, int N, int K) {
  __shared__ __align__(16) unsigned short As[128][40];
  __shared__ __align__(16) unsigned short Bs[128][40];
  const int bm = blockIdx.y * 128;
  const int bn = blockIdx.x * 128;
  const int tid = threadIdx.x;
  const int lane = tid & 63, wave = tid >> 6;
  const int quad = lane >> 4, l16 = lane & 15;
  const int wm = (wave & 1) * 64, wn = (wave >> 1) * 64;

  float4v acc[4][4];
  #pragma unroll
  for (int i = 0; i < 4; ++i)
    #pragma unroll
    for (int j = 0; j < 4; ++j)
      acc[i][j] = (float4v){0.f, 0.f, 0.f, 0.f};

  for (int k0 = 0; k0 < K; k0 += 32) {
    #pragma unroll
    for (int rep = 0; rep < 2; ++rep) {
      int idx = tid + rep * 256;
      int row = idx >> 2, ch = (idx & 3) * 8;
      uint4 av = make_uint4(0u, 0u, 0u, 0u);
      int gm = bm + row;
      if (gm < M) av = *(const uint4*)(A + (size_t)gm * K + k0 + ch);
      *(uint4*)&As[row][ch] = av;
      int gn = bn + row;   // N is a multiple of 128 for all our GEMMs
      uint4 bv = *(const uint4*)(Bt + (size_t)gn * K + k0 + ch);
      *(uint4*)&Bs[row][ch] = bv;
    }
    __syncthreads();
    short8 af[4], bfr[4];
    #pragma unroll
    for (int i = 0; i < 4; ++i)
      af[i] = *(const short8*)&As[wm + i * 16 + l16][quad * 8];
    #pragma unroll
    for (int j = 0; j < 4; ++j)
      bfr[j] = *(const short8*)&Bs[wn + j * 16 + l16][quad * 8];
    #pragma unroll
    for (int i = 0; i < 4; ++i)
      #pragma unroll
      for (int j = 0; j < 4; ++j)
        acc[i][j] = __builtin_amdgcn_mfma_f32_16x16x32_bf16(
            af[i], bfr[j], acc[i][j], 0, 0, 0);
    __syncthreads();
  }

  #pragma unroll
  for (int j = 0; j < 4; ++j) {
    int gn = bn + wn + j * 16 + l16;
    float bv = bias[gn];
    #pragma unroll
    for (int i = 0; i < 4; ++i) {
      int gm0 = bm + wm + i * 16 + quad * 4;
      #pragma unroll
      for (int r = 0; r < 4; ++r) {
        int gm = gm0 + r;
        if (gm < M) {
          float v = acc[i][j][r] + bv;
          size_t off = (size_t)gm * N + gn;
          if (EPI == 0) {
            Cf[off] = v;
          } else if (EPI == 1) {
            Cf[off] = v + res[off];
          } else {
            Cb[off] = f2bf(0.5f * v * (1.f + erff(v * 0.70710678118f)));
          }
        }
      }
    }
  }
}

// ---------------------------------------------------------------------------
// RoPE (unchanged).
// ---------------------------------------------------------------------------
__global__ __launch_bounds__(256) void rope_kernel(float* __restrict__ qkv) {
  int row = blockIdx.x;
  int i = row % NPATCH;
  float* base = qkv + (size_t)row * (3 * DIM);
  int tid = threadIdx.x;
  for (int p = tid; p < 512; p += 256) {
    int s = p >> 8;
    int hh = (p >> 5) & 7;
    int j = p & 31;
    float inv = powf(10000.0f, -(float)j * (1.0f / 32.0f));
    float th = (float)i * inv;
    float sn, cs;
    sincosf(th, &sn, &cs);
    int idx = s * DIM + hh * HD + j;
    float a = base[idx];
    float b2 = base[idx + 32];
    base[idx]      = a * cs - b2 * sn;
    base[idx + 32] = b2 * cs + a * sn;
  }
}

// ---------------------------------------------------------------------------
// Flash-style attention (as R3, passed) — output now bf16 for the proj GEMM.
// ---------------------------------------------------------------------------
#define QT 32
#define JT 64
#define LPAD 65

__global__ __launch_bounds__(256) void attn_kernel(
    const float* __restrict__ qkv, unsigned short* __restrict__ o) {
  const int qt0 = blockIdx.x * QT;
  const int h = blockIdx.y;
  const int b = blockIdx.z;
  const int tid = threadIdx.x;

  __shared__ float Qs[QT][LPAD];
  __shared__ float Ks[JT][LPAD];
  __shared__ float Vs[JT][LPAD];
  __shared__ float Ps[QT][LPAD];
  __shared__ float m_run[QT], l_run[QT], alpha_s[QT];

  {
    int r = tid >> 3;
    int c0 = (tid & 7) * 8;
    int qi = qt0 + r;
    if (qi < NPATCH) {
      const float4* src = (const float4*)(qkv + (size_t)(b * NPATCH + qi) * (3 * DIM) + h * HD + c0);
      float4 v0 = src[0], v1 = src[1];
      Qs[r][c0 + 0] = v0.x * 0.125f; Qs[r][c0 + 1] = v0.y * 0.125f;
      Qs[r][c0 + 2] = v0.z * 0.125f; Qs[r][c0 + 3] = v0.w * 0.125f;
      Qs[r][c0 + 4] = v1.x * 0.125f; Qs[r][c0 + 5] = v1.y * 0.125f;
      Qs[r][c0 + 6] = v1.z * 0.125f; Qs[r][c0 + 7] = v1.w * 0.125f;
    } else {
      #pragma unroll
      for (int u = 0; u < 8; ++u) Qs[r][c0 + u] = 0.f;
    }
  }
  if (tid < QT) { m_run[tid] = -1e30f; l_run[tid] = 0.f; }

  float acc[4][2] = {{0.f, 0.f}, {0.f, 0.f}, {0.f, 0.f}, {0.f, 0.f}};
  __syncthreads();

  for (int j0 = 0; j0 < NPATCH; j0 += JT) {
    {
      int r = tid >> 2;
      int c0 = (tid & 3) * 16;
      int j = j0 + r;
      if (j < NPATCH) {
        const float* base = qkv + (size_t)(b * NPATCH + j) * (3 * DIM) + h * HD;
        const float4* ksrc = (const float4*)(base + DIM + c0);
        const float4* vsrc = (const float4*)(base + 2 * DIM + c0);
        #pragma unroll
        for (int u = 0; u < 4; ++u) {
          float4 kv = ksrc[u];
          Ks[r][c0 + u * 4 + 0] = kv.x; Ks[r][c0 + u * 4 + 1] = kv.y;
          Ks[r][c0 + u * 4 + 2] = kv.z; Ks[r][c0 + u * 4 + 3] = kv.w;
          float4 vv = vsrc[u];
          Vs[r][c0 + u * 4 + 0] = vv.x; Vs[r][c0 + u * 4 + 1] = vv.y;
          Vs[r][c0 + u * 4 + 2] = vv.z; Vs[r][c0 + u * 4 + 3] = vv.w;
        }
      } else {
        #pragma unroll
        for (int u = 0; u < 16; ++u) { Ks[r][c0 + u] = 0.f; Vs[r][c0 + u] = 0.f; }
      }
    }
    __syncthreads();

    {
      int tq = tid >> 5;
      int tk = tid & 31;
      float s[4][2] = {{0.f, 0.f}, {0.f, 0.f}, {0.f, 0.f}, {0.f, 0.f}};
      for (int d = 0; d < HD; ++d) {
        float k0 = Ks[tk][d];
        float k1 = Ks[tk + 32][d];
        #pragma unroll
        for (int i = 0; i < 4; ++i) {
          float qv = Qs[tq + 8 * i][d];
          s[i][0] = fmaf(qv, k0, s[i][0]);
          s[i][1] = fmaf(qv, k1, s[i][1]);
        }
      }
      bool val0 = (j0 + tk) < NPATCH;
      bool val1 = (j0 + tk + 32) < NPATCH;
      #pragma unroll
      for (int i = 0; i < 4; ++i) {
        Ps[tq + 8 * i][tk]      = val0 ? s[i][0] : -1e30f;
        Ps[tq + 8 * i][tk + 32] = val1 ? s[i][1] : -1e30f;
      }
    }
    __syncthreads();

    if (tid < QT) {
      float mold = m_run[tid];
      float tmax = mold;
      for (int j = 0; j < JT; ++j) tmax = fmaxf(tmax, Ps[tid][j]);
      float al = __expf(mold - tmax);
      float ts = 0.f;
      for (int j = 0; j < JT; ++j) {
        float p = __expf(Ps[tid][j] - tmax);
        Ps[tid][j] = p;
        ts += p;
      }
      m_run[tid] = tmax;
      l_run[tid] = l_run[tid] * al + ts;
      alpha_s[tid] = al;
    }
    __syncthreads();

    {
      int to = tid >> 5;
      int td = tid & 31;
      #pragma unroll
      for (int i = 0; i < 4; ++i) {
        float al = alpha_s[to + 8 * i];
        acc[i][0] *= al;
        acc[i][1] *= al;
      }
      for (int j = 0; j < JT; ++j) {
        float v0 = Vs[j][td];
        float v1 = Vs[j][td + 32];
        #pragma unroll
        for (int i = 0; i < 4; ++i) {
          float p = Ps[to + 8 * i][j];
          acc[i][0] = fmaf(p, v0, acc[i][0]);
          acc[i][1] = fmaf(p, v1, acc[i][1]);
        }
      }
    }
    __syncthreads();
  }

  {
    int to = tid >> 5;
    int td = tid & 31;
    #pragma unroll
    for (int i = 0; i < 4; ++i) {
      int q = to + 8 * i;
      int qi = qt0 + q;
      if (qi < NPATCH) {
        float inv = 1.f / l_run[q];
        size_t off = (size_t)(b * NPATCH + qi) * DIM + h * HD + td;
        o[off]      = f2bf(acc[i][0] * inv);
        o[off + 32] = f2bf(acc[i][1] * inv);
      }
    }
  }
}

// ---------------------------------------------------------------------------
extern "C" void kernel_launch(void* const* d_in, const int* in_sizes, int n_in,
                              void* d_out, int out_size, void* d_ws, size_t ws_size,
                              hipStream_t stream) {
  const float* x      = (const float*)d_in[0];
  const float* W_emb  = (const float*)d_in[1];
  const float* b_emb  = (const float*)d_in[2];
  const float* ln1_g  = (const float*)d_in[3];
  const float* ln1_b  = (const float*)d_in[4];
  const float* W_qkv  = (const float*)d_in[5];
  const float* b_qkv  = (const float*)d_in[6];
  const float* W_proj = (const float*)d_in[7];
  const float* b_proj = (const float*)d_in[8];
  const float* ln2_g  = (const float*)d_in[9];
  const float* ln2_b  = (const float*)d_in[10];
  const float* W_mlp1 = (const float*)d_in[11];
  const float* b_mlp1 = (const float*)d_in[12];
  const float* W_mlp2 = (const float*)d_in[13];
  const float* b_mlp2 = (const float*)d_in[14];
  const float* lnf_g  = (const float*)d_in[15];
  const float* lnf_b  = (const float*)d_in[16];
  float* out = (float*)d_out;

  // workspace (bytes): h fp32 8.4M | qkv fp32 25.1M (mid_bf16 aliases) |
  //                    ybf/obf bf16 4.2M (disjoint lifetimes) | Wt bf16 25.2M
  float* h            = (float*)d_ws;
  float* qkv          = h + (size_t)M_ROWS * DIM;
  unsigned short* ybf = (unsigned short*)(qkv + (size_t)M_ROWS * 3 * DIM);
  unsigned short* obf = ybf;                       // alias: ybf dead after its GEMM
  unsigned short* midbf = (unsigned short*)qkv;    // alias: qkv dead after attention
  unsigned short* wqkv_t  = ybf + (size_t)M_ROWS * DIM;
  unsigned short* wproj_t = wqkv_t  + (size_t)NLAYERS * DIM * 3 * DIM;
  unsigned short* wmlp1_t = wproj_t + (size_t)NLAYERS * DIM * DIM;
  unsigned short* wmlp2_t = wmlp1_t + (size_t)NLAYERS * DIM * MLP_HID;

  // weight convert+transpose (once per launch)
  wcvt_kernel<<<dim3(3 * DIM / 32, DIM / 32, NLAYERS), 256, 0, stream>>>(W_qkv,  wqkv_t,  DIM, 3 * DIM);
  wcvt_kernel<<<dim3(DIM / 32, DIM / 32, NLAYERS),     256, 0, stream>>>(W_proj, wproj_t, DIM, DIM);
  wcvt_kernel<<<dim3(MLP_HID / 32, DIM / 32, NLAYERS), 256, 0, stream>>>(W_mlp1, wmlp1_t, DIM, MLP_HID);
  wcvt_kernel<<<dim3(DIM / 32, MLP_HID / 32, NLAYERS), 256, 0, stream>>>(W_mlp2, wmlp2_t, MLP_HID, DIM);

  embed_kernel<<<M_ROWS, 128, 0, stream>>>(x, W_emb, b_emb, out, h);

  const int MT = (M_ROWS + 127) / 128;   // 32
  for (int L = 0; L < NLAYERS; ++L) {
    ln_kernel<true><<<M_ROWS, 64, 0, stream>>>(h, ln1_g + L * DIM, ln1_b + L * DIM, ybf);
    mfma_gemm<0><<<dim3(3 * DIM / 128, MT), 256, 0, stream>>>(
        ybf, wqkv_t + (size_t)L * DIM * 3 * DIM, b_qkv + L * 3 * DIM, nullptr,
        qkv, nullptr, M_ROWS, 3 * DIM, DIM);
    rope_kernel<<<M_ROWS, 256, 0, stream>>>(qkv);
    attn_kernel<<<dim3((NPATCH + QT - 1) / QT, NH, B_SZ), 256, 0, stream>>>(qkv, obf);
    mfma_gemm<1><<<dim3(DIM / 128, MT), 256, 0, stream>>>(
        obf, wproj_t + (size_t)L * DIM * DIM, b_proj + L * DIM, h,
        h, nullptr, M_ROWS, DIM, DIM);
    ln_kernel<true><<<M_ROWS, 64, 0, stream>>>(h, ln2_g + L * DIM, ln2_b + L * DIM, ybf);
    mfma_gemm<2><<<dim3(MLP_HID / 128, MT), 256, 0, stream>>>(
        ybf, wmlp1_t + (size_t)L * DIM * MLP_HID, b_mlp1 + L * MLP_HID, nullptr,
        nullptr, midbf, M_ROWS, MLP_HID, DIM);
    mfma_gemm<1><<<dim3(DIM / 128, MT), 256, 0, stream>>>(
        midbf, wmlp2_t + (size_t)L * MLP_HID * DIM, b_mlp2 + L * DIM, h,
        h, nullptr, M_ROWS, DIM, MLP_HID);
  }

  ln_kernel<false><<<M_ROWS, 64, 0, stream>>>(h, lnf_g, lnf_b, out + (size_t)M_ROWS * DIM);
}

// Round 5
// 1044.297 us; speedup vs baseline: 10.8993x; 1.8414x over previous
//
#include <hip/hip_runtime.h>
#include <hip/hip_bf16.h>
#include <math.h>

#define B_SZ 4
#define T_LEN 8192
#define C_IN 7
#define NPATCH 1023
#define DIM 512
#define NH 8
#define HD 64
#define NLAYERS 4
#define MLP_HID 2048
#define M_ROWS (B_SZ * NPATCH)   // 4092
#define LN_EPS 1e-5f

typedef __attribute__((ext_vector_type(8))) short short8;
typedef __attribute__((ext_vector_type(4))) float float4v;

static __device__ __forceinline__ unsigned short f2bf(float f) {
  __hip_bfloat16 h = __float2bfloat16(f);
  return *reinterpret_cast<unsigned short*>(&h);
}
static __device__ __forceinline__ float bf2f(unsigned short u) {
  return __uint_as_float(((unsigned)u) << 16);
}

// ---------------------------------------------------------------------------
// Patch embedding (fp32 — keeps emb output exact).
// ---------------------------------------------------------------------------
__global__ __launch_bounds__(128) void embed_kernel(
    const float* __restrict__ x, const float* __restrict__ Wemb,
    const float* __restrict__ bemb, float* __restrict__ emb_out,
    float* __restrict__ h) {
  int row = blockIdx.x;
  int b = row / NPATCH, i = row - b * NPATCH;
  __shared__ float patch[112];
  int tid = threadIdx.x;
  if (tid < 112) {
    int c = tid >> 4, p = tid & 15;
    patch[tid] = x[((size_t)b * T_LEN + (size_t)i * 8 + p) * C_IN + c];
  }
  __syncthreads();
  for (int d = tid; d < DIM; d += 128) {
    float acc = bemb[d];
    #pragma unroll 4
    for (int k = 0; k < 112; ++k) acc = fmaf(patch[k], Wemb[k * DIM + d], acc);
    size_t off = (size_t)row * DIM + d;
    emb_out[off] = acc;
    h[off] = acc;
  }
}

// ---------------------------------------------------------------------------
// LayerNorm: one wave per row. BF=true -> bf16 output (GEMM A operand).
// ---------------------------------------------------------------------------
template <bool BF>
__global__ __launch_bounds__(64) void ln_kernel(
    const float* __restrict__ in, const float* __restrict__ g,
    const float* __restrict__ bb, void* __restrict__ outv) {
  int row = blockIdx.x;
  int lane = threadIdx.x;
  const float* xr = in + (size_t)row * DIM;
  float v[8];
  float s = 0.f;
  #pragma unroll
  for (int k = 0; k < 8; ++k) { v[k] = xr[lane + 64 * k]; s += v[k]; }
  #pragma unroll
  for (int off = 32; off; off >>= 1) s += __shfl_down(s, off);
  s = __shfl(s, 0);
  float mu = s * (1.f / DIM);
  float q = 0.f;
  #pragma unroll
  for (int k = 0; k < 8; ++k) { float d = v[k] - mu; q = fmaf(d, d, q); }
  #pragma unroll
  for (int off = 32; off; off >>= 1) q += __shfl_down(q, off);
  q = __shfl(q, 0);
  float rstd = rsqrtf(q * (1.f / DIM) + LN_EPS);
  #pragma unroll
  for (int k = 0; k < 8; ++k) {
    int d = lane + 64 * k;
    float r = (v[k] - mu) * rstd * g[d] + bb[d];
    if (BF)
      ((unsigned short*)outv)[(size_t)row * DIM + d] = f2bf(r);
    else
      ((float*)outv)[(size_t)row * DIM + d] = r;
  }
}

// ---------------------------------------------------------------------------
// Weight convert + transpose: W[K][N] fp32 -> Wt[N][K] bf16 (per layer z).
// ---------------------------------------------------------------------------
__global__ __launch_bounds__(256) void wcvt_kernel(
    const float* __restrict__ W, unsigned short* __restrict__ Wt, int K, int N) {
  __shared__ float tile[32][33];
  int n0 = blockIdx.x * 32, k0 = blockIdx.y * 32, L = blockIdx.z;
  const float* Ws = W + (size_t)L * K * N;
  unsigned short* Wd = Wt + (size_t)L * K * N;
  int tx = threadIdx.x & 31, ty = threadIdx.x >> 5;
  #pragma unroll
  for (int i = 0; i < 4; ++i)
    tile[ty + i * 8][tx] = Ws[(size_t)(k0 + ty + i * 8) * N + n0 + tx];
  __syncthreads();
  #pragma unroll
  for (int i = 0; i < 4; ++i)
    Wd[(size_t)(n0 + ty + i * 8) * K + k0 + tx] = f2bf(tile[tx][ty + i * 8]);
}

// ---------------------------------------------------------------------------
// bf16 MFMA GEMM: C[M][N] = epi(A[M][K] @ Wt[N][K]^T + bias [+res]).
// 128x128 tile, BK=32, 4 waves, each wave 64x64 (4x4 of 16x16x32 MFMA).
// EPI: 0 = bias -> fp32; 1 = bias + res -> fp32; 2 = bias+GELU -> bf16;
//      3 = bias -> bf16.
// ---------------------------------------------------------------------------
template <int EPI>
__global__ __launch_bounds__(256) void mfma_gemm(
    const unsigned short* __restrict__ A, const unsigned short* __restrict__ Bt,
    const float* __restrict__ bias, const float* __restrict__ res,
    float* __restrict__ Cf, unsigned short* __restrict__ Cb,
    int M, int N, int K) {
  __shared__ __align__(16) unsigned short As[128][40];
  __shared__ __align__(16) unsigned short Bs[128][40];
  const int bm = blockIdx.y * 128;
  const int bn = blockIdx.x * 128;
  const int tid = threadIdx.x;
  const int lane = tid & 63, wave = tid >> 6;
  const int quad = lane >> 4, l16 = lane & 15;
  const int wm = (wave & 1) * 64, wn = (wave >> 1) * 64;

  float4v acc[4][4];
  #pragma unroll
  for (int i = 0; i < 4; ++i)
    #pragma unroll
    for (int j = 0; j < 4; ++j)
      acc[i][j] = (float4v){0.f, 0.f, 0.f, 0.f};

  for (int k0 = 0; k0 < K; k0 += 32) {
    #pragma unroll
    for (int rep = 0; rep < 2; ++rep) {
      int idx = tid + rep * 256;
      int row = idx >> 2, ch = (idx & 3) * 8;
      uint4 av = make_uint4(0u, 0u, 0u, 0u);
      int gm = bm + row;
      if (gm < M) av = *(const uint4*)(A + (size_t)gm * K + k0 + ch);
      *(uint4*)&As[row][ch] = av;
      int gn = bn + row;   // N is a multiple of 128 for all our GEMMs
      uint4 bv = *(const uint4*)(Bt + (size_t)gn * K + k0 + ch);
      *(uint4*)&Bs[row][ch] = bv;
    }
    __syncthreads();
    short8 af[4], bfr[4];
    #pragma unroll
    for (int i = 0; i < 4; ++i)
      af[i] = *(const short8*)&As[wm + i * 16 + l16][quad * 8];
    #pragma unroll
    for (int j = 0; j < 4; ++j)
      bfr[j] = *(const short8*)&Bs[wn + j * 16 + l16][quad * 8];
    #pragma unroll
    for (int i = 0; i < 4; ++i)
      #pragma unroll
      for (int j = 0; j < 4; ++j)
        acc[i][j] = __builtin_amdgcn_mfma_f32_16x16x32_bf16(
            af[i], bfr[j], acc[i][j], 0, 0, 0);
    __syncthreads();
  }

  #pragma unroll
  for (int j = 0; j < 4; ++j) {
    int gn = bn + wn + j * 16 + l16;
    float bv = bias[gn];
    #pragma unroll
    for (int i = 0; i < 4; ++i) {
      int gm0 = bm + wm + i * 16 + quad * 4;
      #pragma unroll
      for (int r = 0; r < 4; ++r) {
        int gm = gm0 + r;
        if (gm < M) {
          float v = acc[i][j][r] + bv;
          size_t off = (size_t)gm * N + gn;
          if (EPI == 0) {
            Cf[off] = v;
          } else if (EPI == 1) {
            Cf[off] = v + res[off];
          } else if (EPI == 2) {
            Cb[off] = f2bf(0.5f * v * (1.f + erff(v * 0.70710678118f)));
          } else {
            Cb[off] = f2bf(v);
          }
        }
      }
    }
  }
}

// ---------------------------------------------------------------------------
// RoPE in-place on bf16 qkv[row][1536]; also folds 0.125 scale into Q (exact).
// ---------------------------------------------------------------------------
__global__ __launch_bounds__(256) void rope_kernel(unsigned short* __restrict__ qkvb) {
  int row = blockIdx.x;
  int i = row % NPATCH;
  unsigned short* base = qkvb + (size_t)row * (3 * DIM);
  int tid = threadIdx.x;
  for (int p = tid; p < 512; p += 256) {   // 2 (q,k) * 8 heads * 32 pairs
    int s = p >> 8;
    int hh = (p >> 5) & 7;
    int j = p & 31;
    float inv = powf(10000.0f, -(float)j * (1.0f / 32.0f));
    float th = (float)i * inv;
    float sn, cs;
    sincosf(th, &sn, &cs);
    int idx = s * DIM + hh * HD + j;
    float a = bf2f(base[idx]);
    float b2 = bf2f(base[idx + 32]);
    float r0 = a * cs - b2 * sn;
    float r1 = b2 * cs + a * sn;
    if (s == 0) { r0 *= 0.125f; r1 *= 0.125f; }
    base[idx]      = f2bf(r0);
    base[idx + 32] = f2bf(r1);
  }
}

// ---------------------------------------------------------------------------
// MFMA flash attention. Block = 4 waves = 64 queries; wave w owns queries
// qt0+w*16..+15. Iterate 64-key tiles: K staged [key][dim] bf16, V staged
// transposed [dim][key] bf16. QK^T via mfma_16x16x32_bf16 (A=Q rows, B=K
// rows); S in C-layout (row=quad*4+reg=query, col=l16=key). Online softmax
// stats per query row via xor-shuffles over the 16-lane col group. P -> LDS
// (wave-private) in A-layout, PV via MFMA (B=Vt rows). O stays in C-layout
// accumulators; rescaled by alpha per tile.
// ---------------------------------------------------------------------------
#define APITCH 72

__global__ __launch_bounds__(256) void attn_kernel(
    const unsigned short* __restrict__ qkvb, unsigned short* __restrict__ o) {
  const int qt0 = blockIdx.x * 64;
  const int h = blockIdx.y;
  const int b = blockIdx.z;
  const int tid = threadIdx.x;
  const int lane = tid & 63, wave = tid >> 6;
  const int quad = lane >> 4, l16 = lane & 15;

  __shared__ __align__(16) unsigned short Qs[64][APITCH];
  __shared__ __align__(16) unsigned short Ks[64][APITCH];
  __shared__ __align__(16) unsigned short Vt[HD][APITCH];   // [dim][key]
  __shared__ __align__(16) unsigned short Ps[4][16][APITCH];

  // ---- stage Q tile (already rope'd and 0.125-scaled, bf16) ----
  {
    int r = tid >> 2;              // 0..63
    int c0 = (tid & 3) * 16;       // 0,16,32,48
    int qi = qt0 + r;
    uint4 a = make_uint4(0u, 0u, 0u, 0u), b2 = a;
    if (qi < NPATCH) {
      const uint4* src = (const uint4*)(qkvb + (size_t)(b * NPATCH + qi) * (3 * DIM) + h * HD + c0);
      a = src[0]; b2 = src[1];
    }
    *(uint4*)&Qs[r][c0] = a;
    *(uint4*)&Qs[r][c0 + 8] = b2;
  }
  __syncthreads();

  short8 aq0 = *(const short8*)&Qs[wave * 16 + l16][quad * 8];
  short8 aq1 = *(const short8*)&Qs[wave * 16 + l16][32 + quad * 8];

  float4v accO[4];
  #pragma unroll
  for (int j2 = 0; j2 < 4; ++j2) accO[j2] = (float4v){0.f, 0.f, 0.f, 0.f};
  float m_run[4] = {-1e30f, -1e30f, -1e30f, -1e30f};
  float l_run[4] = {0.f, 0.f, 0.f, 0.f};

  for (int j0 = 0; j0 < NPATCH; j0 += 64) {
    // ---- stage K [key][dim] and V^T [dim][key] ----
    {
      int r = tid >> 2;
      int c0 = (tid & 3) * 16;
      int j = j0 + r;
      uint4 k0 = make_uint4(0u, 0u, 0u, 0u), k1 = k0, v0 = k0, v1 = k0;
      if (j < NPATCH) {
        const unsigned short* baseb = qkvb + (size_t)(b * NPATCH + j) * (3 * DIM) + h * HD;
        k0 = *(const uint4*)(baseb + DIM + c0);
        k1 = *(const uint4*)(baseb + DIM + c0 + 8);
        v0 = *(const uint4*)(baseb + 2 * DIM + c0);
        v1 = *(const uint4*)(baseb + 2 * DIM + c0 + 8);
      }
      *(uint4*)&Ks[r][c0] = k0;
      *(uint4*)&Ks[r][c0 + 8] = k1;
      unsigned short vs[16];
      *(uint4*)&vs[0] = v0;
      *(uint4*)&vs[8] = v1;
      #pragma unroll
      for (int u = 0; u < 16; ++u) Vt[c0 + u][r] = vs[u];
    }
    __syncthreads();

    // ---- S = Q K^T ----
    float4v s[4];
    #pragma unroll
    for (int j = 0; j < 4; ++j) {
      s[j] = (float4v){0.f, 0.f, 0.f, 0.f};
      short8 bk0 = *(const short8*)&Ks[j * 16 + l16][quad * 8];
      short8 bk1 = *(const short8*)&Ks[j * 16 + l16][32 + quad * 8];
      s[j] = __builtin_amdgcn_mfma_f32_16x16x32_bf16(aq0, bk0, s[j], 0, 0, 0);
      s[j] = __builtin_amdgcn_mfma_f32_16x16x32_bf16(aq1, bk1, s[j], 0, 0, 0);
    }

    // ---- online softmax (stats per query row = quad*4+reg) ----
    float mx[4], al[4], ts[4];
    #pragma unroll
    for (int r = 0; r < 4; ++r) {
      mx[r] = fmaxf(fmaxf(s[0][r], s[1][r]), fmaxf(s[2][r], s[3][r]));
    }
    #pragma unroll
    for (int mask = 1; mask < 16; mask <<= 1)
      #pragma unroll
      for (int r = 0; r < 4; ++r)
        mx[r] = fmaxf(mx[r], __shfl_xor(mx[r], mask));
    #pragma unroll
    for (int r = 0; r < 4; ++r) {
      float mnew = fmaxf(m_run[r], mx[r]);
      al[r] = __expf(m_run[r] - mnew);
      m_run[r] = mnew;
      ts[r] = 0.f;
    }
    #pragma unroll
    for (int j = 0; j < 4; ++j) {
      bool valid = (j0 + j * 16 + l16) < NPATCH;
      #pragma unroll
      for (int r = 0; r < 4; ++r) {
        float p = valid ? __expf(s[j][r] - m_run[r]) : 0.f;
        ts[r] += p;
        Ps[wave][quad * 4 + r][j * 16 + l16] = f2bf(p);
      }
    }
    #pragma unroll
    for (int mask = 1; mask < 16; mask <<= 1)
      #pragma unroll
      for (int r = 0; r < 4; ++r)
        ts[r] += __shfl_xor(ts[r], mask);
    #pragma unroll
    for (int r = 0; r < 4; ++r) l_run[r] = l_run[r] * al[r] + ts[r];
    #pragma unroll
    for (int j2 = 0; j2 < 4; ++j2)
      #pragma unroll
      for (int r = 0; r < 4; ++r)
        accO[j2][r] *= al[r];

    // ---- O += P V (wave-private Ps; no barrier needed before reads) ----
    short8 pa0 = *(const short8*)&Ps[wave][l16][quad * 8];
    short8 pa1 = *(const short8*)&Ps[wave][l16][32 + quad * 8];
    #pragma unroll
    for (int j2 = 0; j2 < 4; ++j2) {
      short8 v0 = *(const short8*)&Vt[j2 * 16 + l16][quad * 8];
      short8 v1 = *(const short8*)&Vt[j2 * 16 + l16][32 + quad * 8];
      accO[j2] = __builtin_amdgcn_mfma_f32_16x16x32_bf16(pa0, v0, accO[j2], 0, 0, 0);
      accO[j2] = __builtin_amdgcn_mfma_f32_16x16x32_bf16(pa1, v1, accO[j2], 0, 0, 0);
    }
    __syncthreads();
  }

  // ---- write O (bf16) ----
  #pragma unroll
  for (int r = 0; r < 4; ++r) {
    int qi = qt0 + wave * 16 + quad * 4 + r;
    if (qi < NPATCH) {
      float inv = 1.f / l_run[r];
      size_t off = (size_t)(b * NPATCH + qi) * DIM + h * HD + l16;
      #pragma unroll
      for (int j2 = 0; j2 < 4; ++j2)
        o[off + j2 * 16] = f2bf(accO[j2][r] * inv);
    }
  }
}

// ---------------------------------------------------------------------------
extern "C" void kernel_launch(void* const* d_in, const int* in_sizes, int n_in,
                              void* d_out, int out_size, void* d_ws, size_t ws_size,
                              hipStream_t stream) {
  const float* x      = (const float*)d_in[0];
  const float* W_emb  = (const float*)d_in[1];
  const float* b_emb  = (const float*)d_in[2];
  const float* ln1_g  = (const float*)d_in[3];
  const float* ln1_b  = (const float*)d_in[4];
  const float* W_qkv  = (const float*)d_in[5];
  const float* b_qkv  = (const float*)d_in[6];
  const float* W_proj = (const float*)d_in[7];
  const float* b_proj = (const float*)d_in[8];
  const float* ln2_g  = (const float*)d_in[9];
  const float* ln2_b  = (const float*)d_in[10];
  const float* W_mlp1 = (const float*)d_in[11];
  const float* b_mlp1 = (const float*)d_in[12];
  const float* W_mlp2 = (const float*)d_in[13];
  const float* b_mlp2 = (const float*)d_in[14];
  const float* lnf_g  = (const float*)d_in[15];
  const float* lnf_b  = (const float*)d_in[16];
  float* out = (float*)d_out;

  // workspace (bytes):
  //   h fp32 8.4M | shared region 16.8M (qkvb bf16 M*1536 / midbf bf16 M*2048,
  //   disjoint lifetimes) | ybf/obf bf16 4.2M | Wt bf16 25.2M  -> ~54.6M
  float* h              = (float*)d_ws;
  unsigned short* qkvb  = (unsigned short*)(h + (size_t)M_ROWS * DIM);
  unsigned short* midbf = qkvb;   // alias: qkvb dead after attn; mid born at mlp1
  unsigned short* ybf   = qkvb + (size_t)M_ROWS * MLP_HID;
  unsigned short* obf   = ybf;    // alias: ybf dead after its GEMM
  unsigned short* wqkv_t  = ybf + (size_t)M_ROWS * DIM;
  unsigned short* wproj_t = wqkv_t  + (size_t)NLAYERS * DIM * 3 * DIM;
  unsigned short* wmlp1_t = wproj_t + (size_t)NLAYERS * DIM * DIM;
  unsigned short* wmlp2_t = wmlp1_t + (size_t)NLAYERS * DIM * MLP_HID;

  wcvt_kernel<<<dim3(3 * DIM / 32, DIM / 32, NLAYERS), 256, 0, stream>>>(W_qkv,  wqkv_t,  DIM, 3 * DIM);
  wcvt_kernel<<<dim3(DIM / 32, DIM / 32, NLAYERS),     256, 0, stream>>>(W_proj, wproj_t, DIM, DIM);
  wcvt_kernel<<<dim3(MLP_HID / 32, DIM / 32, NLAYERS), 256, 0, stream>>>(W_mlp1, wmlp1_t, DIM, MLP_HID);
  wcvt_kernel<<<dim3(DIM / 32, MLP_HID / 32, NLAYERS), 256, 0, stream>>>(W_mlp2, wmlp2_t, MLP_HID, DIM);

  embed_kernel<<<M_ROWS, 128, 0, stream>>>(x, W_emb, b_emb, out, h);

  const int MT = (M_ROWS + 127) / 128;   // 32
  for (int L = 0; L < NLAYERS; ++L) {
    ln_kernel<true><<<M_ROWS, 64, 0, stream>>>(h, ln1_g + L * DIM, ln1_b + L * DIM, ybf);
    mfma_gemm<3><<<dim3(3 * DIM / 128, MT), 256, 0, stream>>>(
        ybf, wqkv_t + (size_t)L * DIM * 3 * DIM, b_qkv + L * 3 * DIM, nullptr,
        nullptr, qkvb, M_ROWS, 3 * DIM, DIM);
    rope_kernel<<<M_ROWS, 256, 0, stream>>>(qkvb);
    attn_kernel<<<dim3((NPATCH + 63) / 64, NH, B_SZ), 256, 0, stream>>>(qkvb, obf);
    mfma_gemm<1><<<dim3(DIM / 128, MT), 256, 0, stream>>>(
        obf, wproj_t + (size_t)L * DIM * DIM, b_proj + L * DIM, h,
        h, nullptr, M_ROWS, DIM, DIM);
    ln_kernel<true><<<M_ROWS, 64, 0, stream>>>(h, ln2_g + L * DIM, ln2_b + L * DIM, ybf);
    mfma_gemm<2><<<dim3(MLP_HID / 128, MT), 256, 0, stream>>>(
        ybf, wmlp1_t + (size_t)L * DIM * MLP_HID, b_mlp1 + L * MLP_HID, nullptr,
        nullptr, midbf, M_ROWS, MLP_HID, DIM);
    mfma_gemm<1><<<dim3(DIM / 128, MT), 256, 0, stream>>>(
        midbf, wmlp2_t + (size_t)L * MLP_HID * DIM, b_mlp2 + L * DIM, h,
        h, nullptr, M_ROWS, DIM, MLP_HID);
  }

  ln_kernel<false><<<M_ROWS, 64, 0, stream>>>(h, lnf_g, lnf_b, out + (size_t)M_ROWS * DIM);
}

// Round 6
// 857.917 us; speedup vs baseline: 13.2672x; 1.2172x over previous
//
#include <hip/hip_runtime.h>
#include <hip/hip_bf16.h>
#include <math.h>

#define B_SZ 4
#define T_LEN 8192
#define C_IN 7
#define NPATCH 1023
#define DIM 512
#define NH 8
#define HD 64
#define NLAYERS 4
#define MLP_HID 2048
#define M_ROWS (B_SZ * NPATCH)   // 4092
#define LN_EPS 1e-5f

typedef __attribute__((ext_vector_type(8))) short short8;
typedef __attribute__((ext_vector_type(4))) float float4v;

static __device__ __forceinline__ unsigned short f2bf(float f) {
  __hip_bfloat16 h = __float2bfloat16(f);
  return *reinterpret_cast<unsigned short*>(&h);
}
static __device__ __forceinline__ float bf2f(unsigned short u) {
  return __uint_as_float(((unsigned)u) << 16);
}

// ---------------------------------------------------------------------------
// Patch embedding (fp32 — keeps emb output exact).
// ---------------------------------------------------------------------------
__global__ __launch_bounds__(128) void embed_kernel(
    const float* __restrict__ x, const float* __restrict__ Wemb,
    const float* __restrict__ bemb, float* __restrict__ emb_out,
    float* __restrict__ h) {
  int row = blockIdx.x;
  int b = row / NPATCH, i = row - b * NPATCH;
  __shared__ float patch[112];
  int tid = threadIdx.x;
  if (tid < 112) {
    int c = tid >> 4, p = tid & 15;
    patch[tid] = x[((size_t)b * T_LEN + (size_t)i * 8 + p) * C_IN + c];
  }
  __syncthreads();
  for (int d = tid; d < DIM; d += 128) {
    float acc = bemb[d];
    #pragma unroll 4
    for (int k = 0; k < 112; ++k) acc = fmaf(patch[k], Wemb[k * DIM + d], acc);
    size_t off = (size_t)row * DIM + d;
    emb_out[off] = acc;
    h[off] = acc;
  }
}

// ---------------------------------------------------------------------------
// LayerNorm: 4 rows per block (one wave per row). BF=true -> bf16 output.
// ---------------------------------------------------------------------------
template <bool BF>
__global__ __launch_bounds__(256) void ln_kernel(
    const float* __restrict__ in, const float* __restrict__ g,
    const float* __restrict__ bb, void* __restrict__ outv, int M) {
  int row = blockIdx.x * 4 + (threadIdx.x >> 6);
  if (row >= M) return;
  int lane = threadIdx.x & 63;
  const float* xr = in + (size_t)row * DIM;
  float v[8];
  float s = 0.f;
  #pragma unroll
  for (int k = 0; k < 8; ++k) { v[k] = xr[lane + 64 * k]; s += v[k]; }
  #pragma unroll
  for (int off = 32; off; off >>= 1) s += __shfl_down(s, off);
  s = __shfl(s, 0);
  float mu = s * (1.f / DIM);
  float q = 0.f;
  #pragma unroll
  for (int k = 0; k < 8; ++k) { float d = v[k] - mu; q = fmaf(d, d, q); }
  #pragma unroll
  for (int off = 32; off; off >>= 1) q += __shfl_down(q, off);
  q = __shfl(q, 0);
  float rstd = rsqrtf(q * (1.f / DIM) + LN_EPS);
  #pragma unroll
  for (int k = 0; k < 8; ++k) {
    int d = lane + 64 * k;
    float r = (v[k] - mu) * rstd * g[d] + bb[d];
    if (BF)
      ((unsigned short*)outv)[(size_t)row * DIM + d] = f2bf(r);
    else
      ((float*)outv)[(size_t)row * DIM + d] = r;
  }
}

// ---------------------------------------------------------------------------
// Weight convert + transpose: W[K][N] fp32 -> Wt[N][K] bf16 (per layer z).
// ---------------------------------------------------------------------------
__global__ __launch_bounds__(256) void wcvt_kernel(
    const float* __restrict__ W, unsigned short* __restrict__ Wt, int K, int N) {
  __shared__ float tile[32][33];
  int n0 = blockIdx.x * 32, k0 = blockIdx.y * 32, L = blockIdx.z;
  const float* Ws = W + (size_t)L * K * N;
  unsigned short* Wd = Wt + (size_t)L * K * N;
  int tx = threadIdx.x & 31, ty = threadIdx.x >> 5;
  #pragma unroll
  for (int i = 0; i < 4; ++i)
    tile[ty + i * 8][tx] = Ws[(size_t)(k0 + ty + i * 8) * N + n0 + tx];
  __syncthreads();
  #pragma unroll
  for (int i = 0; i < 4; ++i)
    Wd[(size_t)(n0 + ty + i * 8) * K + k0 + tx] = f2bf(tile[tx][ty + i * 8]);
}

// ---------------------------------------------------------------------------
// bf16 MFMA GEMM: C[M][N] = epi(A[M][K] @ Wt[N][K]^T + bias [+res]).
// 128x128 tile, BK=32, 4 waves, each wave 64x64 (4x4 of 16x16x32 MFMA).
// Split-K: blockIdx.z selects K-range [z*Ks, z*Ks+Ks); inv_s = 1/gridDim.z.
// EPI: 0 = bias -> fp32; 1 = bias + res -> fp32; 2 = bias+GELU -> bf16;
//      3 = bias -> bf16; 4 = split-K partial: atomicAdd(Cf, acc + bias*inv_s).
// ---------------------------------------------------------------------------
template <int EPI>
__global__ __launch_bounds__(256) void mfma_gemm(
    const unsigned short* __restrict__ A, const unsigned short* __restrict__ Bt,
    const float* __restrict__ bias, const float* __restrict__ res,
    float* __restrict__ Cf, unsigned short* __restrict__ Cb,
    int M, int N, int K, int Ks, float inv_s) {
  __shared__ __align__(16) unsigned short As[128][40];
  __shared__ __align__(16) unsigned short Bs[128][40];
  const int bm = blockIdx.y * 128;
  const int bn = blockIdx.x * 128;
  const int tid = threadIdx.x;
  const int lane = tid & 63, wave = tid >> 6;
  const int quad = lane >> 4, l16 = lane & 15;
  const int wm = (wave & 1) * 64, wn = (wave >> 1) * 64;
  const int kb = blockIdx.z * Ks;

  float4v acc[4][4];
  #pragma unroll
  for (int i = 0; i < 4; ++i)
    #pragma unroll
    for (int j = 0; j < 4; ++j)
      acc[i][j] = (float4v){0.f, 0.f, 0.f, 0.f};

  for (int k0 = kb; k0 < kb + Ks; k0 += 32) {
    #pragma unroll
    for (int rep = 0; rep < 2; ++rep) {
      int idx = tid + rep * 256;
      int row = idx >> 2, ch = (idx & 3) * 8;
      uint4 av = make_uint4(0u, 0u, 0u, 0u);
      int gm = bm + row;
      if (gm < M) av = *(const uint4*)(A + (size_t)gm * K + k0 + ch);
      *(uint4*)&As[row][ch] = av;
      int gn = bn + row;   // N is a multiple of 128 for all our GEMMs
      uint4 bv = *(const uint4*)(Bt + (size_t)gn * K + k0 + ch);
      *(uint4*)&Bs[row][ch] = bv;
    }
    __syncthreads();
    short8 af[4], bfr[4];
    #pragma unroll
    for (int i = 0; i < 4; ++i)
      af[i] = *(const short8*)&As[wm + i * 16 + l16][quad * 8];
    #pragma unroll
    for (int j = 0; j < 4; ++j)
      bfr[j] = *(const short8*)&Bs[wn + j * 16 + l16][quad * 8];
    #pragma unroll
    for (int i = 0; i < 4; ++i)
      #pragma unroll
      for (int j = 0; j < 4; ++j)
        acc[i][j] = __builtin_amdgcn_mfma_f32_16x16x32_bf16(
            af[i], bfr[j], acc[i][j], 0, 0, 0);
    __syncthreads();
  }

  #pragma unroll
  for (int j = 0; j < 4; ++j) {
    int gn = bn + wn + j * 16 + l16;
    float bv = bias[gn] * inv_s;
    #pragma unroll
    for (int i = 0; i < 4; ++i) {
      int gm0 = bm + wm + i * 16 + quad * 4;
      #pragma unroll
      for (int r = 0; r < 4; ++r) {
        int gm = gm0 + r;
        if (gm < M) {
          float v = acc[i][j][r] + bv;
          size_t off = (size_t)gm * N + gn;
          if (EPI == 0) {
            Cf[off] = v;
          } else if (EPI == 1) {
            Cf[off] = v + res[off];
          } else if (EPI == 2) {
            Cb[off] = f2bf(0.5f * v * (1.f + erff(v * 0.70710678118f)));
          } else if (EPI == 3) {
            Cb[off] = f2bf(v);
          } else {
            atomicAdd(&Cf[off], v);
          }
        }
      }
    }
  }
}

// ---------------------------------------------------------------------------
// RoPE cos/sin table: tab[i*32+j] = (cos, sin) of i * 10000^(-j/32).
// ---------------------------------------------------------------------------
__global__ __launch_bounds__(256) void rope_tab_kernel(float2* __restrict__ tab) {
  int idx = blockIdx.x * 256 + threadIdx.x;
  if (idx >= NPATCH * 32) return;
  int i = idx >> 5, j = idx & 31;
  float inv = powf(10000.0f, -(float)j * (1.0f / 32.0f));
  float sn, cs;
  sincosf((float)i * inv, &sn, &cs);
  tab[idx] = make_float2(cs, sn);
}

// ---------------------------------------------------------------------------
// RoPE in-place on bf16 qkv[row][1536] using the table; folds 0.125 into Q.
// ---------------------------------------------------------------------------
__global__ __launch_bounds__(256) void rope_kernel(
    unsigned short* __restrict__ qkvb, const float2* __restrict__ tab) {
  int row = blockIdx.x;
  int i = row % NPATCH;
  unsigned short* base = qkvb + (size_t)row * (3 * DIM);
  int tid = threadIdx.x;
  for (int p = tid; p < 512; p += 256) {   // 2 (q,k) * 8 heads * 32 pairs
    int s = p >> 8;
    int hh = (p >> 5) & 7;
    int j = p & 31;
    float2 cssn = tab[i * 32 + j];
    int idx = s * DIM + hh * HD + j;
    float a = bf2f(base[idx]);
    float b2 = bf2f(base[idx + 32]);
    float r0 = a * cssn.x - b2 * cssn.y;
    float r1 = b2 * cssn.x + a * cssn.y;
    if (s == 0) { r0 *= 0.125f; r1 *= 0.125f; }
    base[idx]      = f2bf(r0);
    base[idx + 32] = f2bf(r1);
  }
}

// ---------------------------------------------------------------------------
// MFMA flash attention (R5, passed). Block = 4 waves = 64 queries.
// ---------------------------------------------------------------------------
#define APITCH 72

__global__ __launch_bounds__(256) void attn_kernel(
    const unsigned short* __restrict__ qkvb, unsigned short* __restrict__ o) {
  const int qt0 = blockIdx.x * 64;
  const int h = blockIdx.y;
  const int b = blockIdx.z;
  const int tid = threadIdx.x;
  const int lane = tid & 63, wave = tid >> 6;
  const int quad = lane >> 4, l16 = lane & 15;

  __shared__ __align__(16) unsigned short Qs[64][APITCH];
  __shared__ __align__(16) unsigned short Ks[64][APITCH];
  __shared__ __align__(16) unsigned short Vt[HD][APITCH];   // [dim][key]
  __shared__ __align__(16) unsigned short Ps[4][16][APITCH];

  {
    int r = tid >> 2;
    int c0 = (tid & 3) * 16;
    int qi = qt0 + r;
    uint4 a = make_uint4(0u, 0u, 0u, 0u), b2 = a;
    if (qi < NPATCH) {
      const uint4* src = (const uint4*)(qkvb + (size_t)(b * NPATCH + qi) * (3 * DIM) + h * HD + c0);
      a = src[0]; b2 = src[1];
    }
    *(uint4*)&Qs[r][c0] = a;
    *(uint4*)&Qs[r][c0 + 8] = b2;
  }
  __syncthreads();

  short8 aq0 = *(const short8*)&Qs[wave * 16 + l16][quad * 8];
  short8 aq1 = *(const short8*)&Qs[wave * 16 + l16][32 + quad * 8];

  float4v accO[4];
  #pragma unroll
  for (int j2 = 0; j2 < 4; ++j2) accO[j2] = (float4v){0.f, 0.f, 0.f, 0.f};
  float m_run[4] = {-1e30f, -1e30f, -1e30f, -1e30f};
  float l_run[4] = {0.f, 0.f, 0.f, 0.f};

  for (int j0 = 0; j0 < NPATCH; j0 += 64) {
    {
      int r = tid >> 2;
      int c0 = (tid & 3) * 16;
      int j = j0 + r;
      uint4 k0 = make_uint4(0u, 0u, 0u, 0u), k1 = k0, v0 = k0, v1 = k0;
      if (j < NPATCH) {
        const unsigned short* baseb = qkvb + (size_t)(b * NPATCH + j) * (3 * DIM) + h * HD;
        k0 = *(const uint4*)(baseb + DIM + c0);
        k1 = *(const uint4*)(baseb + DIM + c0 + 8);
        v0 = *(const uint4*)(baseb + 2 * DIM + c0);
        v1 = *(const uint4*)(baseb + 2 * DIM + c0 + 8);
      }
      *(uint4*)&Ks[r][c0] = k0;
      *(uint4*)&Ks[r][c0 + 8] = k1;
      unsigned short vs[16];
      *(uint4*)&vs[0] = v0;
      *(uint4*)&vs[8] = v1;
      #pragma unroll
      for (int u = 0; u < 16; ++u) Vt[c0 + u][r] = vs[u];
    }
    __syncthreads();

    float4v s[4];
    #pragma unroll
    for (int j = 0; j < 4; ++j) {
      s[j] = (float4v){0.f, 0.f, 0.f, 0.f};
      short8 bk0 = *(const short8*)&Ks[j * 16 + l16][quad * 8];
      short8 bk1 = *(const short8*)&Ks[j * 16 + l16][32 + quad * 8];
      s[j] = __builtin_amdgcn_mfma_f32_16x16x32_bf16(aq0, bk0, s[j], 0, 0, 0);
      s[j] = __builtin_amdgcn_mfma_f32_16x16x32_bf16(aq1, bk1, s[j], 0, 0, 0);
    }

    float mx[4], al[4], ts[4];
    #pragma unroll
    for (int r = 0; r < 4; ++r)
      mx[r] = fmaxf(fmaxf(s[0][r], s[1][r]), fmaxf(s[2][r], s[3][r]));
    #pragma unroll
    for (int mask = 1; mask < 16; mask <<= 1)
      #pragma unroll
      for (int r = 0; r < 4; ++r)
        mx[r] = fmaxf(mx[r], __shfl_xor(mx[r], mask));
    #pragma unroll
    for (int r = 0; r < 4; ++r) {
      float mnew = fmaxf(m_run[r], mx[r]);
      al[r] = __expf(m_run[r] - mnew);
      m_run[r] = mnew;
      ts[r] = 0.f;
    }
    #pragma unroll
    for (int j = 0; j < 4; ++j) {
      bool valid = (j0 + j * 16 + l16) < NPATCH;
      #pragma unroll
      for (int r = 0; r < 4; ++r) {
        float p = valid ? __expf(s[j][r] - m_run[r]) : 0.f;
        ts[r] += p;
        Ps[wave][quad * 4 + r][j * 16 + l16] = f2bf(p);
      }
    }
    #pragma unroll
    for (int mask = 1; mask < 16; mask <<= 1)
      #pragma unroll
      for (int r = 0; r < 4; ++r)
        ts[r] += __shfl_xor(ts[r], mask);
    #pragma unroll
    for (int r = 0; r < 4; ++r) l_run[r] = l_run[r] * al[r] + ts[r];
    #pragma unroll
    for (int j2 = 0; j2 < 4; ++j2)
      #pragma unroll
      for (int r = 0; r < 4; ++r)
        accO[j2][r] *= al[r];

    short8 pa0 = *(const short8*)&Ps[wave][l16][quad * 8];
    short8 pa1 = *(const short8*)&Ps[wave][l16][32 + quad * 8];
    #pragma unroll
    for (int j2 = 0; j2 < 4; ++j2) {
      short8 v0 = *(const short8*)&Vt[j2 * 16 + l16][quad * 8];
      short8 v1 = *(const short8*)&Vt[j2 * 16 + l16][32 + quad * 8];
      accO[j2] = __builtin_amdgcn_mfma_f32_16x16x32_bf16(pa0, v0, accO[j2], 0, 0, 0);
      accO[j2] = __builtin_amdgcn_mfma_f32_16x16x32_bf16(pa1, v1, accO[j2], 0, 0, 0);
    }
    __syncthreads();
  }

  #pragma unroll
  for (int r = 0; r < 4; ++r) {
    int qi = qt0 + wave * 16 + quad * 4 + r;
    if (qi < NPATCH) {
      float inv = 1.f / l_run[r];
      size_t off = (size_t)(b * NPATCH + qi) * DIM + h * HD + l16;
      #pragma unroll
      for (int j2 = 0; j2 < 4; ++j2)
        o[off + j2 * 16] = f2bf(accO[j2][r] * inv);
    }
  }
}

// ---------------------------------------------------------------------------
// h[m][n] — split-K targets get bias folded in the GEMM (bias*inv_s per split).
// ---------------------------------------------------------------------------
extern "C" void kernel_launch(void* const* d_in, const int* in_sizes, int n_in,
                              void* d_out, int out_size, void* d_ws, size_t ws_size,
                              hipStream_t stream) {
  const float* x      = (const float*)d_in[0];
  const float* W_emb  = (const float*)d_in[1];
  const float* b_emb  = (const float*)d_in[2];
  const float* ln1_g  = (const float*)d_in[3];
  const float* ln1_b  = (const float*)d_in[4];
  const float* W_qkv  = (const float*)d_in[5];
  const float* b_qkv  = (const float*)d_in[6];
  const float* W_proj = (const float*)d_in[7];
  const float* b_proj = (const float*)d_in[8];
  const float* ln2_g  = (const float*)d_in[9];
  const float* ln2_b  = (const float*)d_in[10];
  const float* W_mlp1 = (const float*)d_in[11];
  const float* b_mlp1 = (const float*)d_in[12];
  const float* W_mlp2 = (const float*)d_in[13];
  const float* b_mlp2 = (const float*)d_in[14];
  const float* lnf_g  = (const float*)d_in[15];
  const float* lnf_b  = (const float*)d_in[16];
  float* out = (float*)d_out;

  // workspace: h fp32 8.4M | shared 16.8M (qkvb/midbf) | ybf/obf 4.2M |
  //            Wt bf16 25.2M | rope tab 262K   -> ~54.9M
  float* h              = (float*)d_ws;
  unsigned short* qkvb  = (unsigned short*)(h + (size_t)M_ROWS * DIM);
  unsigned short* midbf = qkvb;   // alias: qkvb dead after attn; mid born at mlp1
  unsigned short* ybf   = qkvb + (size_t)M_ROWS * MLP_HID;
  unsigned short* obf   = ybf;    // alias: ybf dead after its GEMM
  unsigned short* wqkv_t  = ybf + (size_t)M_ROWS * DIM;
  unsigned short* wproj_t = wqkv_t  + (size_t)NLAYERS * DIM * 3 * DIM;
  unsigned short* wmlp1_t = wproj_t + (size_t)NLAYERS * DIM * DIM;
  unsigned short* wmlp2_t = wmlp1_t + (size_t)NLAYERS * DIM * MLP_HID;
  float2* rtab = (float2*)(wmlp2_t + (size_t)NLAYERS * MLP_HID * DIM);

  wcvt_kernel<<<dim3(3 * DIM / 32, DIM / 32, NLAYERS), 256, 0, stream>>>(W_qkv,  wqkv_t,  DIM, 3 * DIM);
  wcvt_kernel<<<dim3(DIM / 32, DIM / 32, NLAYERS),     256, 0, stream>>>(W_proj, wproj_t, DIM, DIM);
  wcvt_kernel<<<dim3(MLP_HID / 32, DIM / 32, NLAYERS), 256, 0, stream>>>(W_mlp1, wmlp1_t, DIM, MLP_HID);
  wcvt_kernel<<<dim3(DIM / 32, MLP_HID / 32, NLAYERS), 256, 0, stream>>>(W_mlp2, wmlp2_t, MLP_HID, DIM);
  rope_tab_kernel<<<(NPATCH * 32 + 255) / 256, 256, 0, stream>>>(rtab);

  embed_kernel<<<M_ROWS, 128, 0, stream>>>(x, W_emb, b_emb, out, h);

  const int MT = (M_ROWS + 127) / 128;   // 32
  const int LNG = (M_ROWS + 3) / 4;      // 1023
  for (int L = 0; L < NLAYERS; ++L) {
    ln_kernel<true><<<LNG, 256, 0, stream>>>(h, ln1_g + L * DIM, ln1_b + L * DIM, ybf, M_ROWS);
    mfma_gemm<3><<<dim3(3 * DIM / 128, MT), 256, 0, stream>>>(
        ybf, wqkv_t + (size_t)L * DIM * 3 * DIM, b_qkv + L * 3 * DIM, nullptr,
        nullptr, qkvb, M_ROWS, 3 * DIM, DIM, DIM, 1.f);
    rope_kernel<<<M_ROWS, 256, 0, stream>>>(qkvb, rtab);
    attn_kernel<<<dim3((NPATCH + 63) / 64, NH, B_SZ), 256, 0, stream>>>(qkvb, obf);
    // proj: split-K=2 -> h += o @ Wp + bias   (256 blocks)
    mfma_gemm<4><<<dim3(DIM / 128, MT, 2), 256, 0, stream>>>(
        obf, wproj_t + (size_t)L * DIM * DIM, b_proj + L * DIM, nullptr,
        h, nullptr, M_ROWS, DIM, DIM, DIM / 2, 0.5f);
    ln_kernel<true><<<LNG, 256, 0, stream>>>(h, ln2_g + L * DIM, ln2_b + L * DIM, ybf, M_ROWS);
    mfma_gemm<2><<<dim3(MLP_HID / 128, MT), 256, 0, stream>>>(
        ybf, wmlp1_t + (size_t)L * DIM * MLP_HID, b_mlp1 + L * MLP_HID, nullptr,
        nullptr, midbf, M_ROWS, MLP_HID, DIM, DIM, 1.f);
    // mlp2: split-K=4 -> h += mid @ Wm2 + bias   (512 blocks)
    mfma_gemm<4><<<dim3(DIM / 128, MT, 4), 256, 0, stream>>>(
        midbf, wmlp2_t + (size_t)L * MLP_HID * DIM, b_mlp2 + L * DIM, nullptr,
        h, nullptr, M_ROWS, DIM, MLP_HID, MLP_HID / 4, 0.25f);
  }

  ln_kernel<false><<<LNG, 256, 0, stream>>>(h, lnf_g, lnf_b, out + (size_t)M_ROWS * DIM, M_ROWS);
}